// Round 9
// baseline (349.218 us; speedup 1.0000x reference)
//
#include <hip/hip_runtime.h>

#define NCH 128   // EMBED
#define NH  8     // HEADS
#define HID 512
#define SLOPE 0.2f
#define BN_EPS 1e-5f
#define LDP 136   // padded LDS inner dim (bf16 units) - used by feat path only
#define NPW 4     // nodes per wave in gather
#define CHUNK 2048  // edges per bin_scatter block

typedef __attribute__((ext_vector_type(8))) short short8;     // 8 bf16 (4 VGPRs)
typedef __attribute__((ext_vector_type(4))) float floatx4;    // 4 fp32 acc

__device__ inline unsigned short f2bf(float f) {  // RNE f32 -> bf16 bits
  unsigned u = __float_as_uint(f);
  u += 0x7fffu + ((u >> 16) & 1u);
  return (unsigned short)(u >> 16);
}
__device__ inline float bflo(unsigned u) { return __uint_as_float(u << 16); }
__device__ inline float bfhi(unsigned u) { return __uint_as_float(u & 0xffff0000u); }

// ---------------- fused prep: weights + zero fills ----------------
__global__ void prep_all(const float* __restrict__ W, unsigned short* __restrict__ WT,
                         const float* __restrict__ W1, unsigned short* __restrict__ w1f,
                         const float* __restrict__ W2, unsigned short* __restrict__ w2f,
                         float* __restrict__ stats, int* __restrict__ cnt, int N) {
  int b = blockIdx.x, tid = threadIdx.x;
  if (b < 64) {
    int i = b * 256 + tid;
    int n = i >> 7, k = i & 127;
    WT[i] = f2bf(W[k * NCH + n]);
  } else if (b < 320) {
    int i = (b - 64) * 256 + tid;
    int ntile = i >> 11, kk = (i >> 9) & 3, lane = (i >> 3) & 63, j = i & 7;
    int k = kk * 32 + (lane >> 4) * 8 + j;
    int n = ntile * 16 + (lane & 15);
    w1f[i] = f2bf(W1[k * HID + n]);
  } else if (b < 576) {
    int i = (b - 320) * 256 + tid;
    int ch = i >> 14, nt = (i >> 11) & 7, kk = (i >> 9) & 3, lane = (i >> 3) & 63, j = i & 7;
    int k = ch * 128 + kk * 32 + (lane >> 4) * 8 + j;
    int n = nt * 16 + (lane & 15);
    w2f[i] = f2bf(W2[k * NCH + n]);
  } else if (b < 596) {
    int i = (b - 576) * 256 + tid;   // < 5120 exactly
    ((float4*)stats)[i] = make_float4(0.f, 0.f, 0.f, 0.f);
  } else {
    int i = (b - 596) * 256 + tid;
    int n4 = (N + 3) >> 2;
    if (i < n4) ((int4*)cnt)[i] = make_int4(0, 0, 0, 0);
  }
}

// ---------------- fused: featb = bf16(x@W) + er epilogue  |  edge histogram ----------------
__global__ __launch_bounds__(256) void feat_hist(const float* __restrict__ x,
                                                 const unsigned short* __restrict__ WT,  // WT[n][k]
                                                 const float* __restrict__ attn_r,
                                                 unsigned short* __restrict__ featb,
                                                 float* __restrict__ er,
                                                 int N,
                                                 const int* __restrict__ dst, int* __restrict__ cnt,
                                                 int E, int FB) {
  __shared__ unsigned short rowX[64 * LDP];
  __shared__ unsigned short wt[128 * LDP];
  __shared__ float arL[128];
  if (blockIdx.x >= FB) {     // ---- hist part (no LDS, no sync) ----
    int i = (blockIdx.x - FB) * 256 + threadIdx.x;
    if (i < E) atomicAdd(&cnt[dst[i]], 1);
    return;
  }
  int tid = threadIdx.x;
  int r0 = blockIdx.x * 64;
  int lane = tid & 63, wid = tid >> 6;
  int quad = lane >> 4, lc = lane & 15;
  int mrow = (wid & 1) * 32;
  int chalf = (wid >> 1) * 64;

  if (tid < 128) arL[tid] = attn_r[tid];
  {
    int n = tid >> 1, kg = (tid & 1) * 64;
    const uint4* g = (const uint4*)(WT + n * NCH + kg);
    uint4* l = (uint4*)&wt[n * LDP + kg];
    for (int i = 0; i < 8; i++) l[i] = g[i];
  }
  {
    int r = tid >> 2, kg = (tid & 3) * 32;
    int gr = r0 + r;
    unsigned short tmp[32];
    if (gr < N) {
      const float4* gp = (const float4*)(x + (size_t)gr * NCH + kg);
      for (int i = 0; i < 8; i++) {
        float4 v = gp[i];
        tmp[i * 4 + 0] = f2bf(v.x); tmp[i * 4 + 1] = f2bf(v.y);
        tmp[i * 4 + 2] = f2bf(v.z); tmp[i * 4 + 3] = f2bf(v.w);
      }
    } else {
      for (int i = 0; i < 32; i++) tmp[i] = 0;
    }
    uint4* l = (uint4*)&rowX[r * LDP + kg];
    const uint4* s = (const uint4*)tmp;
    for (int i = 0; i < 4; i++) l[i] = s[i];
  }
  __syncthreads();

  floatx4 acc[2][4];
  for (int rt = 0; rt < 2; rt++) for (int tt = 0; tt < 4; tt++) acc[rt][tt] = (floatx4)(0.f);
  for (int kk = 0; kk < 4; kk++) {
    short8 a0 = *(const short8*)&rowX[(mrow + lc) * LDP + kk * 32 + quad * 8];
    short8 a1 = *(const short8*)&rowX[(mrow + 16 + lc) * LDP + kk * 32 + quad * 8];
    for (int tt = 0; tt < 4; tt++) {
      short8 b = *(const short8*)&wt[(chalf + tt * 16 + lc) * LDP + kk * 32 + quad * 8];
      acc[0][tt] = __builtin_amdgcn_mfma_f32_16x16x32_bf16(a0, b, acc[0][tt], 0, 0, 0);
      acc[1][tt] = __builtin_amdgcn_mfma_f32_16x16x32_bf16(a1, b, acc[1][tt], 0, 0, 0);
    }
  }
  __syncthreads();
  for (int rt = 0; rt < 2; rt++)
    for (int tt = 0; tt < 4; tt++)
      for (int r = 0; r < 4; r++)
        rowX[(mrow + rt * 16 + quad * 4 + r) * LDP + chalf + tt * 16 + lc] = f2bf(acc[rt][tt][r]);
  __syncthreads();
  {
    int r = tid >> 2, kg = (tid & 3) * 32;
    int gr = r0 + r;
    if (gr < N) {
      uint4* gp = (uint4*)(featb + (size_t)gr * NCH + kg);
      const uint4* l = (const uint4*)&rowX[r * LDP + kg];
      for (int i = 0; i < 4; i++) gp[i] = l[i];
    }
  }
  // fused er: 512 (row,head) pairs from the LDS featb tile
  for (int p = tid; p < 512; p += 256) {
    int row = p >> 3, h = p & 7;
    int gr = r0 + row;
    if (gr < N) {
      const unsigned* rp = (const unsigned*)&rowX[row * LDP + h * 16];
      float sr = 0.f;
      for (int q = 0; q < 8; q++) {
        unsigned u = rp[q];
        int c = h * 16 + 2 * q;
        sr += bflo(u) * arL[c] + bfhi(u) * arL[c + 1];
      }
      er[gr * NH + h] = sr;
    }
  }
}

// ---------------- counting sort of edges by dst ----------------
__global__ void scan_part(const int* __restrict__ cnt, int* __restrict__ off,
                          int* __restrict__ bsum, int N) {
  __shared__ int sh[256];
  int t = threadIdx.x, i = blockIdx.x * 256 + t;
  int v = (i < N) ? cnt[i] : 0;
  sh[t] = v; __syncthreads();
  for (int d = 1; d < 256; d <<= 1) {
    int u = (t >= d) ? sh[t - d] : 0;
    __syncthreads();
    sh[t] += u;
    __syncthreads();
  }
  if (i < N) off[i] = sh[t] - v;
  if (t == 255) bsum[blockIdx.x] = sh[255];
}

// scan_add with built-in top-level scan; also initializes per-bucket cursor
__global__ void scan_add2(int* __restrict__ off, const int* __restrict__ bsum,
                          int* __restrict__ bktcur, int N, int nb) {
  __shared__ int sh[256];
  int t = threadIdx.x;
  int v = (t < nb) ? bsum[t] : 0;
  sh[t] = v; __syncthreads();
  for (int d = 1; d < 256; d <<= 1) {
    int u = (t >= d) ? sh[t - d] : 0;
    __syncthreads();
    sh[t] += u;
    __syncthreads();
  }
  int pref = (blockIdx.x > 0) ? sh[blockIdx.x - 1] : 0;
  int i = blockIdx.x * 256 + t;
  if (i < N) {
    int w = off[i] + pref;
    off[i] = w;
    if (t == 0) bktcur[blockIdx.x] = w;
  }
}

// ---------------- pass 1: bin edges by dst>>8 into bucket-major (src,dst) runs ----------------
__global__ __launch_bounds__(256) void bin_scatter(const int* __restrict__ src,
                                                   const int* __restrict__ dst,
                                                   int* __restrict__ bktcur,
                                                   uint2* __restrict__ ebuf, int E) {
  __shared__ int bc[256];
  __shared__ int bbase[256];
  int tid = threadIdx.x;
  int s = blockIdx.x * CHUNK;
  int e = min(s + CHUNK, E);
  bc[tid] = 0;
  __syncthreads();
  for (int i = s + tid; i < e; i += 256) atomicAdd(&bc[dst[i] >> 8], 1);
  __syncthreads();
  int c = bc[tid];
  if (c > 0) bbase[tid] = atomicAdd(&bktcur[tid], c);
  __syncthreads();
  bc[tid] = 0;
  __syncthreads();
  for (int i = s + tid; i < e; i += 256) {
    int d = dst[i];
    int b = d >> 8;
    int r = atomicAdd(&bc[b], 1);
    ebuf[bbase[b] + r] = make_uint2((unsigned)src[i], (unsigned)d);
  }
}

// ---------------- pass 2: per-bucket final scatter with LDS cursors ----------------
__global__ __launch_bounds__(256) void final_scatter(const uint2* __restrict__ ebuf,
                                                     const int* __restrict__ off,
                                                     int* __restrict__ ssrc,
                                                     int E, int N, int NBK) {
  __shared__ int lcur[256];
  __shared__ int sbeg, send;
  int tid = threadIdx.x;
  int b = blockIdx.x;
  int n0 = b * 256;
  int node = n0 + tid;
  lcur[tid] = (node < N) ? off[node] : 0;
  if (tid == 0) {
    sbeg = off[n0];
    send = (b == NBK - 1) ? E : off[n0 + 256];
  }
  __syncthreads();
  int beg = sbeg, end = send;
  for (int i = beg + tid; i < end; i += 256) {
    uint2 ed = ebuf[i];
    int r = atomicAdd(&lcur[(int)ed.y - n0], 1);
    ssrc[r] = (int)ed.x;
  }
}

// ---------------- gather + skip + bias + fused BN1 stats ----------------
// v8: all-node metadata (off/cnt/er) + FIRST ssrc OCTET prefetched at wave entry
// into scalar regs -> node-boundary dependent-load bubble (off->ssrc->featb) removed;
// every node's first featb loads issue immediately at node start.
__global__ __launch_bounds__(256) void gat_gather8(const int* __restrict__ ssrc,
                                                   const int* __restrict__ off,
                                                   const int* __restrict__ cnt,
                                                   const float* __restrict__ attn_l,
                                                   const float* __restrict__ er,
                                                   const unsigned short* __restrict__ featb,
                                                   const float* __restrict__ x,
                                                   const float* __restrict__ gatb,
                                                   float* __restrict__ hbuf,
                                                   float* __restrict__ stats, int N) {
  __shared__ float ps[4][128], pq[4][128];
  int tid = threadIdx.x;
  int lane = tid & 63, w = tid >> 6;
  int hme = lane >> 3;         // head of this lane's channel pair
  int c0 = 2 * lane;
  float2 al2 = *(const float2*)(attn_l + c0);
  float alx = al2.x, aly = al2.y;
  float gb0 = gatb[c0], gb1 = gatb[c0 + 1];
  float s0 = 0.f, s1 = 0.f, q0 = 0.f, q1 = 0.f;
  int base = blockIdx.x * (4 * NPW) + w * NPW;

  // ---- upfront prefetch: metadata + first ssrc octet for all NPW nodes ----
  int begA[NPW], numA[NPW], pfs[NPW][8];
  float erhA[NPW];
  #pragma unroll
  for (int j = 0; j < NPW; j++) {
    int nd = base + j;
    if (nd < N) {
      int nds = __builtin_amdgcn_readfirstlane(nd);
      begA[j] = __builtin_amdgcn_readfirstlane(off[nds]);
      numA[j] = __builtin_amdgcn_readfirstlane(cnt[nds]);
      erhA[j] = er[nds * NH + hme];
    } else { begA[j] = 0; numA[j] = 0; erhA[j] = 0.f; }
  }
  #pragma unroll
  for (int j = 0; j < NPW; j++) {
    const int* sp0 = ssrc + begA[j];
    int n = numA[j] < 8 ? numA[j] : 8;
    #pragma unroll
    for (int k = 0; k < 8; k++)
      pfs[j][k] = (k < n) ? __builtin_amdgcn_readfirstlane(sp0[k]) : 0;
  }

  // octet processing (identical math/order to gather7's octet)
  auto octet = [&](int n0, int n1, int n2, int n3, int n4, int n5, int n6, int n7,
                   float erh, float& acc0, float& acc1, float& den) {
    unsigned f0 = ((const unsigned*)(featb + (size_t)n0 * NCH))[lane];
    unsigned f1 = ((const unsigned*)(featb + (size_t)n1 * NCH))[lane];
    unsigned f2 = ((const unsigned*)(featb + (size_t)n2 * NCH))[lane];
    unsigned f3 = ((const unsigned*)(featb + (size_t)n3 * NCH))[lane];
    unsigned f4 = ((const unsigned*)(featb + (size_t)n4 * NCH))[lane];
    unsigned f5 = ((const unsigned*)(featb + (size_t)n5 * NCH))[lane];
    unsigned f6 = ((const unsigned*)(featb + (size_t)n6 * NCH))[lane];
    unsigned f7 = ((const unsigned*)(featb + (size_t)n7 * NCH))[lane];
    float p0 = bflo(f0) * alx + bfhi(f0) * aly;
    float p1 = bflo(f1) * alx + bfhi(f1) * aly;
    float p2 = bflo(f2) * alx + bfhi(f2) * aly;
    float p3 = bflo(f3) * alx + bfhi(f3) * aly;
    float p4 = bflo(f4) * alx + bfhi(f4) * aly;
    float p5 = bflo(f5) * alx + bfhi(f5) * aly;
    float p6 = bflo(f6) * alx + bfhi(f6) * aly;
    float p7 = bflo(f7) * alx + bfhi(f7) * aly;
    p0 += __shfl_xor(p0, 1); p1 += __shfl_xor(p1, 1);
    p2 += __shfl_xor(p2, 1); p3 += __shfl_xor(p3, 1);
    p4 += __shfl_xor(p4, 1); p5 += __shfl_xor(p5, 1);
    p6 += __shfl_xor(p6, 1); p7 += __shfl_xor(p7, 1);
    p0 += __shfl_xor(p0, 2); p1 += __shfl_xor(p1, 2);
    p2 += __shfl_xor(p2, 2); p3 += __shfl_xor(p3, 2);
    p4 += __shfl_xor(p4, 2); p5 += __shfl_xor(p5, 2);
    p6 += __shfl_xor(p6, 2); p7 += __shfl_xor(p7, 2);
    p0 += __shfl_xor(p0, 4); p1 += __shfl_xor(p1, 4);
    p2 += __shfl_xor(p2, 4); p3 += __shfl_xor(p3, 4);
    p4 += __shfl_xor(p4, 4); p5 += __shfl_xor(p5, 4);
    p6 += __shfl_xor(p6, 4); p7 += __shfl_xor(p7, 4);
    float e0 = p0 + erh, e1 = p1 + erh, e2 = p2 + erh, e3 = p3 + erh;
    float e4 = p4 + erh, e5 = p5 + erh, e6 = p6 + erh, e7 = p7 + erh;
    e0 = e0 > 0.f ? e0 : SLOPE * e0;  e1 = e1 > 0.f ? e1 : SLOPE * e1;
    e2 = e2 > 0.f ? e2 : SLOPE * e2;  e3 = e3 > 0.f ? e3 : SLOPE * e3;
    e4 = e4 > 0.f ? e4 : SLOPE * e4;  e5 = e5 > 0.f ? e5 : SLOPE * e5;
    e6 = e6 > 0.f ? e6 : SLOPE * e6;  e7 = e7 > 0.f ? e7 : SLOPE * e7;
    float w0 = __expf(e0), w1 = __expf(e1), w2 = __expf(e2), w3 = __expf(e3);
    float w4 = __expf(e4), w5 = __expf(e5), w6 = __expf(e6), w7 = __expf(e7);
    acc0 += w0 * bflo(f0) + w1 * bflo(f1) + w2 * bflo(f2) + w3 * bflo(f3)
          + w4 * bflo(f4) + w5 * bflo(f5) + w6 * bflo(f6) + w7 * bflo(f7);
    acc1 += w0 * bfhi(f0) + w1 * bfhi(f1) + w2 * bfhi(f2) + w3 * bfhi(f3)
          + w4 * bfhi(f4) + w5 * bfhi(f5) + w6 * bfhi(f6) + w7 * bfhi(f7);
    den  += w0 + w1 + w2 + w3 + w4 + w5 + w6 + w7;
  };

  for (int j = 0; j < NPW; j++) {
    int node = base + j;
    if (node >= N) break;
    node = __builtin_amdgcn_readfirstlane(node);
    float erh = erhA[j];
    int beg = begA[j], num = numA[j];
    const int* sp = ssrc + beg;
    float acc0 = 0.f, acc1 = 0.f, den = 0.f;
    int i = 0;
    if (num >= 8) {   // first octet from prefetched indices (featb loads issue NOW)
      octet(pfs[j][0], pfs[j][1], pfs[j][2], pfs[j][3],
            pfs[j][4], pfs[j][5], pfs[j][6], pfs[j][7], erh, acc0, acc1, den);
      i = 8;
      for (; i + 8 <= num; i += 8) {
        int n0 = __builtin_amdgcn_readfirstlane(sp[i + 0]);
        int n1 = __builtin_amdgcn_readfirstlane(sp[i + 1]);
        int n2 = __builtin_amdgcn_readfirstlane(sp[i + 2]);
        int n3 = __builtin_amdgcn_readfirstlane(sp[i + 3]);
        int n4 = __builtin_amdgcn_readfirstlane(sp[i + 4]);
        int n5 = __builtin_amdgcn_readfirstlane(sp[i + 5]);
        int n6 = __builtin_amdgcn_readfirstlane(sp[i + 6]);
        int n7 = __builtin_amdgcn_readfirstlane(sp[i + 7]);
        octet(n0, n1, n2, n3, n4, n5, n6, n7, erh, acc0, acc1, den);
      }
    }
    for (; i < num; i++) {
      int s = (i < 8) ? pfs[j][i] : __builtin_amdgcn_readfirstlane(sp[i]);
      unsigned f = ((const unsigned*)(featb + (size_t)s * NCH))[lane];
      float p = bflo(f) * alx + bfhi(f) * aly;
      p += __shfl_xor(p, 1); p += __shfl_xor(p, 2); p += __shfl_xor(p, 4);
      float e = p + erh;
      e = e > 0.f ? e : SLOPE * e;
      float wv = __expf(e);
      acc0 += wv * bflo(f); acc1 += wv * bfhi(f); den += wv;
    }
    float inv = den > 0.f ? 1.f / den : 0.f;
    float2 xv = *(const float2*)(x + (size_t)node * NCH + c0);
    float h0 = xv.x + acc0 * inv + gb0;
    float h1 = xv.y + acc1 * inv + gb1;
    *(float2*)(hbuf + (size_t)node * NCH + c0) = make_float2(h0, h1);
    s0 += h0; s1 += h1; q0 += h0 * h0; q1 += h1 * h1;
  }
  ps[w][c0] = s0; ps[w][c0 + 1] = s1;
  pq[w][c0] = q0; pq[w][c0 + 1] = q1;
  __syncthreads();
  if (tid < 128) {
    float ss = ps[0][tid] + ps[1][tid] + ps[2][tid] + ps[3][tid];
    float qq = pq[0][tid] + pq[1][tid] + pq[2][tid] + pq[3][tid];
    int rep = blockIdx.x & 7;   // 8-way replicated, CONTIGUOUS (few dirty lines)
    atomicAdd(&stats[rep * 128 + tid], ss);
    atomicAdd(&stats[1024 + rep * 128 + tid], qq);
  }
}

// ---------------- fused BN1-finalize + BN1 + FFN: hid^T trick, rowA in registers ----------------
__global__ __launch_bounds__(512, 4) void ffn_mfma2(const float* __restrict__ hbuf,
                                                    const float* __restrict__ g1, const float* __restrict__ be1,
                                                    const unsigned short* __restrict__ w1f,
                                                    const unsigned short* __restrict__ w2f,
                                                    const float* __restrict__ b1, const float* __restrict__ b2,
                                                    float* __restrict__ t, float* __restrict__ stats, int N) {
  __shared__ unsigned short w1t[16384];   // 32 KB (chunk weights; reused as BN1-row stash in epilogue)
  __shared__ unsigned short w2t[16384];   // 32 KB
  __shared__ unsigned short scr[8][512];  // 8 KB wave-private transpose scratch (1 frag)
  __shared__ float b1L[512];              // 2 KB
  __shared__ float psc[128], psh[128], b2L[128], csum[128], csq[128];  // 2.5 KB
  int tid = threadIdx.x;
  int lane = tid & 63, wid = tid >> 6;
  int quad = lane >> 4, lc = lane & 15;
  int r0 = blockIdx.x * 128;

  b1L[tid] = b1[tid];
  if (tid < 128) {
    float s = 0.f, sq = 0.f;
    for (int r = 0; r < 8; r++) {
      s  += stats[r * 128 + tid];
      sq += stats[1024 + r * 128 + tid];
    }
    float m = s / (float)N;
    float v = sq / (float)N - m * m;
    float rsv = rsqrtf(v + BN_EPS);
    float scv = g1[tid] * rsv;
    psc[tid] = scv;
    psh[tid] = be1[tid] - scv * m;
    b2L[tid] = b2[tid];
    csum[tid] = 0.f; csq[tid] = 0.f;
  }

  int arow = r0 + wid * 16 + lc;
  float4 av[4][2];
  for (int kk = 0; kk < 4; kk++) {
    if (arow < N) {
      const float4* p = (const float4*)(hbuf + (size_t)arow * NCH + kk * 32 + quad * 8);
      av[kk][0] = p[0]; av[kk][1] = p[1];
    } else {
      av[kk][0] = make_float4(0.f, 0.f, 0.f, 0.f);
      av[kk][1] = make_float4(0.f, 0.f, 0.f, 0.f);
    }
  }
  __syncthreads();   // psc/psh ready

  short8 rowA[4];
  for (int kk = 0; kk < 4; kk++) {
    int c = kk * 32 + quad * 8;
    float4 s0 = *(float4*)&psc[c], s1 = *(float4*)&psc[c + 4];
    float4 h0 = *(float4*)&psh[c], h1 = *(float4*)&psh[c + 4];
    short8 r;
    r[0] = (short)f2bf(av[kk][0].x * s0.x + h0.x);
    r[1] = (short)f2bf(av[kk][0].y * s0.y + h0.y);
    r[2] = (short)f2bf(av[kk][0].z * s0.z + h0.z);
    r[3] = (short)f2bf(av[kk][0].w * s0.w + h0.w);
    r[4] = (short)f2bf(av[kk][1].x * s1.x + h1.x);
    r[5] = (short)f2bf(av[kk][1].y * s1.y + h1.y);
    r[6] = (short)f2bf(av[kk][1].z * s1.z + h1.z);
    r[7] = (short)f2bf(av[kk][1].w * s1.w + h1.w);
    rowA[kk] = r;
  }

  floatx4 acc2[8];
  for (int nt = 0; nt < 8; nt++) acc2[nt] = (floatx4)(0.f);

  for (int ch = 0; ch < 4; ch++) {
    __syncthreads();
    {
      const uint4* g1p = (const uint4*)(w1f + ch * 16384);
      const uint4* g2p = (const uint4*)(w2f + ch * 16384);
      uint4* l1 = (uint4*)w1t;
      uint4* l2 = (uint4*)w2t;
      for (int r = 0; r < 4; r++) {
        l1[tid + r * 512] = g1p[tid + r * 512];
        l2[tid + r * 512] = g2p[tid + r * 512];
      }
    }
    __syncthreads();

    for (int kk = 0; kk < 4; kk++) {
      floatx4 d0 = (floatx4)(0.f), d1 = (floatx4)(0.f);
      int t0 = 2 * kk, t1 = 2 * kk + 1;
      for (int kp = 0; kp < 4; kp++) {
        short8 a0 = *(const short8*)&w1t[(t0 * 4 + kp) * 512 + lane * 8];
        short8 a1 = *(const short8*)&w1t[(t1 * 4 + kp) * 512 + lane * 8];
        d0 = __builtin_amdgcn_mfma_f32_16x16x32_bf16(a0, rowA[kp], d0, 0, 0, 0);
        d1 = __builtin_amdgcn_mfma_f32_16x16x32_bf16(a1, rowA[kp], d1, 0, 0, 0);
      }
      {
        int bi0 = ch * 128 + t0 * 16 + 4 * quad;
        float4 bv0 = *(float4*)&b1L[bi0];
        float4 bv1 = *(float4*)&b1L[bi0 + 16];
        float v0, v1, v2, v3;
        unsigned lo, hi;
        int sidx;
        v0 = fmaxf(d0[0] + bv0.x, 0.f); v1 = fmaxf(d0[1] + bv0.y, 0.f);
        v2 = fmaxf(d0[2] + bv0.z, 0.f); v3 = fmaxf(d0[3] + bv0.w, 0.f);
        lo = (unsigned)f2bf(v0) | ((unsigned)f2bf(v1) << 16);
        hi = (unsigned)f2bf(v2) | ((unsigned)f2bf(v3) << 16);
        sidx = ((quad >> 1) * 16 + lc) * 8 + 4 * (quad & 1);
        *(uint2*)&scr[wid][sidx] = make_uint2(lo, hi);
        v0 = fmaxf(d1[0] + bv1.x, 0.f); v1 = fmaxf(d1[1] + bv1.y, 0.f);
        v2 = fmaxf(d1[2] + bv1.z, 0.f); v3 = fmaxf(d1[3] + bv1.w, 0.f);
        lo = (unsigned)f2bf(v0) | ((unsigned)f2bf(v1) << 16);
        hi = (unsigned)f2bf(v2) | ((unsigned)f2bf(v3) << 16);
        sidx = ((2 + (quad >> 1)) * 16 + lc) * 8 + 4 * (quad & 1);
        *(uint2*)&scr[wid][sidx] = make_uint2(lo, hi);
      }
      short8 a2 = *(const short8*)&scr[wid][lane * 8];
      for (int nt = 0; nt < 8; nt++) {
        short8 bfr = *(const short8*)&w2t[(nt * 4 + kk) * 512 + lane * 8];
        acc2[nt] = __builtin_amdgcn_mfma_f32_16x16x32_bf16(a2, bfr, acc2[nt], 0, 0, 0);
      }
    }
  }

  __syncthreads();   // all waves done reading w1t/w2t
  {
    unsigned short* stash = w1t;  // [wave][row16][col]
    for (int kk = 0; kk < 4; kk++)
      *(short8*)&stash[wid * 2048 + lc * 128 + kk * 32 + quad * 8] = rowA[kk];
  }
  __syncthreads();

  for (int nt = 0; nt < 8; nt++) {
    int col = nt * 16 + lc;
    float b2v = b2L[col];
    float s = 0.f, q = 0.f;
    for (int reg = 0; reg < 4; reg++) {
      int grow = r0 + wid * 16 + quad * 4 + reg;
      if (grow < N) {
        float base = bflo((unsigned)w1t[wid * 2048 + (quad * 4 + reg) * 128 + col]);
        float tv = base + acc2[nt][reg] + b2v;
        t[(size_t)grow * NCH + col] = tv;
        s += tv; q += tv * tv;
      }
    }
    s += __shfl_xor(s, 16); s += __shfl_xor(s, 32);
    q += __shfl_xor(q, 16); q += __shfl_xor(q, 32);
    if (quad == 0) { atomicAdd(&csum[col], s); atomicAdd(&csq[col], q); }
  }
  __syncthreads();
  if (tid < 128) {
    atomicAdd(&stats[16384 + tid * 16], csum[tid]);
    atomicAdd(&stats[18432 + tid * 16], csq[tid]);
  }
}

// ---------------- BN2 finalize + apply -> out (float4 vectorized) ----------------
__global__ __launch_bounds__(256) void bn2_apply2(const float* __restrict__ t,
                                                  const float* __restrict__ g, const float* __restrict__ b,
                                                  const float* __restrict__ stats,
                                                  float* __restrict__ out, int N) {
  __shared__ float scs[128], shs[128];
  int tid = threadIdx.x;
  if (tid < 128) {
    float s = stats[16384 + tid * 16], sq = stats[18432 + tid * 16];
    float m = s / (float)N;
    float v = sq / (float)N - m * m;
    float rsv = rsqrtf(v + BN_EPS);
    float gg = g[tid] * rsv;
    scs[tid] = gg;
    shs[tid] = b[tid] - gg * m;
  }
  __syncthreads();
  int i = blockIdx.x * 256 + tid;
  int tot4 = N * 32;   // N*128/4
  if (i < tot4) {
    float4 v = ((const float4*)t)[i];
    int c = (i & 31) * 4;
    float4 o;
    o.x = v.x * scs[c + 0] + shs[c + 0];
    o.y = v.y * scs[c + 1] + shs[c + 1];
    o.z = v.z * scs[c + 2] + shs[c + 2];
    o.w = v.w * scs[c + 3] + shs[c + 3];
    ((float4*)out)[i] = o;
  }
}

extern "C" void kernel_launch(void* const* d_in, const int* in_sizes, int n_in,
                              void* d_out, int out_size, void* d_ws, size_t ws_size,
                              hipStream_t stream) {
  const float* x       = (const float*)d_in[0];
  const int*   src     = (const int*)d_in[1];
  const int*   dst     = (const int*)d_in[2];
  const float* W       = (const float*)d_in[3];
  const float* attn_l  = (const float*)d_in[4];
  const float* attn_r  = (const float*)d_in[5];
  const float* gatb    = (const float*)d_in[6];
  const float* gamma1  = (const float*)d_in[7];
  const float* beta1   = (const float*)d_in[8];
  const float* gamma2  = (const float*)d_in[9];
  const float* beta2   = (const float*)d_in[10];
  const float* W1      = (const float*)d_in[11];
  const float* b1      = (const float*)d_in[12];
  const float* W2      = (const float*)d_in[13];
  const float* b2      = (const float*)d_in[14];
  float* out = (float*)d_out;

  const int N = in_sizes[0] / NCH;   // 50000
  const int E = in_sizes[1];         // 800000
  const int nb = (N + 255) / 256;    // scan blocks == bucket count
  const int EB = (E + 255) / 256;    // edge blocks (hist)
  const int FB = (N + 63) / 64;      // feat blocks
  const int BB = (E + CHUNK - 1) / CHUNK;  // bin_scatter blocks

  float* hbuf  = (float*)d_ws;             // N*128 f32 (pre-BN1 h)
  float* t     = hbuf + (size_t)N * NCH;   // N*128 f32 (pre-BN2 t)
  float* er    = t + (size_t)N * NCH;      // N*8
  float* stats = er + (size_t)N * NH;      // 20480 floats (BN1 8-rep contiguous + BN2)
  unsigned short* featb = (unsigned short*)(stats + 20480);  // N*128 bf16
  unsigned short* WT    = featb + (size_t)N * NCH;           // 128*128 bf16
  unsigned short* w1f   = WT + NCH * NCH;                    // 512*128 bf16 (frag order)
  unsigned short* w2f   = w1f + HID * NCH;                   // 128*512 bf16 (frag order)
  int* cnt    = (int*)(w2f + HID * NCH);                     // N
  int* off    = cnt + N;                                     // N
  int* bktcur = off + N;                                     // 256
  int* bsum   = bktcur + 256;                                // 256
  int* ssrc   = bsum + 256;                                  // E
  uint2* ebuf = (uint2*)(ssrc + E);                          // E uint2 (8B each)

  const int cb = (((N + 3) / 4) + 255) / 256;
  prep_all<<<596 + cb, 256, 0, stream>>>(W, WT, W1, w1f, W2, w2f, stats, cnt, N);

  feat_hist<<<FB + EB, 256, 0, stream>>>(x, WT, attn_r, featb, er, N, dst, cnt, E, FB);

  scan_part<<<nb, 256, 0, stream>>>(cnt, off, bsum, N);
  scan_add2<<<nb, 256, 0, stream>>>(off, bsum, bktcur, N, nb);

  bin_scatter<<<BB, 256, 0, stream>>>(src, dst, bktcur, ebuf, E);
  final_scatter<<<nb, 256, 0, stream>>>(ebuf, off, ssrc, E, N, nb);

  gat_gather8<<<(N + 4 * NPW - 1) / (4 * NPW), 256, 0, stream>>>(ssrc, off, cnt, attn_l, er,
                                                                 featb, x, gatb, hbuf, stats, N);

  ffn_mfma2<<<(N + 127) / 128, 512, 0, stream>>>(hbuf, gamma1, beta1,
                                                 w1f, w2f, b1, b2, t, stats, N);

  bn2_apply2<<<(N * 32 + 255) / 256, 256, 0, stream>>>(t, gamma2, beta2, stats, out, N);
}

// Round 10
// 268.391 us; speedup vs baseline: 1.3012x; 1.3012x over previous
//
#include <hip/hip_runtime.h>

#define NCH 128   // EMBED
#define NH  8     // HEADS
#define HID 512
#define SLOPE 0.2f
#define BN_EPS 1e-5f
#define LDP 136   // padded LDS inner dim (bf16 units) - used by feat path only
#define NPW 2     // nodes per wave in gather (finer blocks -> better tail fill)
#define CHUNK 2048  // edges per bin_scatter block

typedef __attribute__((ext_vector_type(8))) short short8;     // 8 bf16 (4 VGPRs)
typedef __attribute__((ext_vector_type(4))) float floatx4;    // 4 fp32 acc

__device__ inline unsigned short f2bf(float f) {  // RNE f32 -> bf16 bits
  unsigned u = __float_as_uint(f);
  u += 0x7fffu + ((u >> 16) & 1u);
  return (unsigned short)(u >> 16);
}
__device__ inline float bflo(unsigned u) { return __uint_as_float(u << 16); }
__device__ inline float bfhi(unsigned u) { return __uint_as_float(u & 0xffff0000u); }

// ---------------- fused prep: weights + zero fills ----------------
__global__ void prep_all(const float* __restrict__ W, unsigned short* __restrict__ WT,
                         const float* __restrict__ W1, unsigned short* __restrict__ w1f,
                         const float* __restrict__ W2, unsigned short* __restrict__ w2f,
                         float* __restrict__ stats, int* __restrict__ cnt, int N) {
  int b = blockIdx.x, tid = threadIdx.x;
  if (b < 64) {
    int i = b * 256 + tid;
    int n = i >> 7, k = i & 127;
    WT[i] = f2bf(W[k * NCH + n]);
  } else if (b < 320) {
    int i = (b - 64) * 256 + tid;
    int ntile = i >> 11, kk = (i >> 9) & 3, lane = (i >> 3) & 63, j = i & 7;
    int k = kk * 32 + (lane >> 4) * 8 + j;
    int n = ntile * 16 + (lane & 15);
    w1f[i] = f2bf(W1[k * HID + n]);
  } else if (b < 576) {
    int i = (b - 320) * 256 + tid;
    int ch = i >> 14, nt = (i >> 11) & 7, kk = (i >> 9) & 3, lane = (i >> 3) & 63, j = i & 7;
    int k = ch * 128 + kk * 32 + (lane >> 4) * 8 + j;
    int n = nt * 16 + (lane & 15);
    w2f[i] = f2bf(W2[k * NCH + n]);
  } else if (b < 596) {
    int i = (b - 576) * 256 + tid;   // < 5120 exactly
    ((float4*)stats)[i] = make_float4(0.f, 0.f, 0.f, 0.f);
  } else {
    int i = (b - 596) * 256 + tid;
    int n4 = (N + 3) >> 2;
    if (i < n4) ((int4*)cnt)[i] = make_int4(0, 0, 0, 0);
  }
}

// ---------------- fused: featb = bf16(x@W) + er epilogue  |  edge histogram ----------------
__global__ __launch_bounds__(256) void feat_hist(const float* __restrict__ x,
                                                 const unsigned short* __restrict__ WT,  // WT[n][k]
                                                 const float* __restrict__ attn_r,
                                                 unsigned short* __restrict__ featb,
                                                 float* __restrict__ er,
                                                 int N,
                                                 const int* __restrict__ dst, int* __restrict__ cnt,
                                                 int E, int FB) {
  __shared__ unsigned short rowX[64 * LDP];
  __shared__ unsigned short wt[128 * LDP];
  __shared__ float arL[128];
  if (blockIdx.x >= FB) {     // ---- hist part (no LDS, no sync) ----
    int i = (blockIdx.x - FB) * 256 + threadIdx.x;
    if (i < E) atomicAdd(&cnt[dst[i]], 1);
    return;
  }
  int tid = threadIdx.x;
  int r0 = blockIdx.x * 64;
  int lane = tid & 63, wid = tid >> 6;
  int quad = lane >> 4, lc = lane & 15;
  int mrow = (wid & 1) * 32;
  int chalf = (wid >> 1) * 64;

  if (tid < 128) arL[tid] = attn_r[tid];
  {
    int n = tid >> 1, kg = (tid & 1) * 64;
    const uint4* g = (const uint4*)(WT + n * NCH + kg);
    uint4* l = (uint4*)&wt[n * LDP + kg];
    for (int i = 0; i < 8; i++) l[i] = g[i];
  }
  {
    int r = tid >> 2, kg = (tid & 3) * 32;
    int gr = r0 + r;
    unsigned short tmp[32];
    if (gr < N) {
      const float4* gp = (const float4*)(x + (size_t)gr * NCH + kg);
      for (int i = 0; i < 8; i++) {
        float4 v = gp[i];
        tmp[i * 4 + 0] = f2bf(v.x); tmp[i * 4 + 1] = f2bf(v.y);
        tmp[i * 4 + 2] = f2bf(v.z); tmp[i * 4 + 3] = f2bf(v.w);
      }
    } else {
      for (int i = 0; i < 32; i++) tmp[i] = 0;
    }
    uint4* l = (uint4*)&rowX[r * LDP + kg];
    const uint4* s = (const uint4*)tmp;
    for (int i = 0; i < 4; i++) l[i] = s[i];
  }
  __syncthreads();

  floatx4 acc[2][4];
  for (int rt = 0; rt < 2; rt++) for (int tt = 0; tt < 4; tt++) acc[rt][tt] = (floatx4)(0.f);
  for (int kk = 0; kk < 4; kk++) {
    short8 a0 = *(const short8*)&rowX[(mrow + lc) * LDP + kk * 32 + quad * 8];
    short8 a1 = *(const short8*)&rowX[(mrow + 16 + lc) * LDP + kk * 32 + quad * 8];
    for (int tt = 0; tt < 4; tt++) {
      short8 b = *(const short8*)&wt[(chalf + tt * 16 + lc) * LDP + kk * 32 + quad * 8];
      acc[0][tt] = __builtin_amdgcn_mfma_f32_16x16x32_bf16(a0, b, acc[0][tt], 0, 0, 0);
      acc[1][tt] = __builtin_amdgcn_mfma_f32_16x16x32_bf16(a1, b, acc[1][tt], 0, 0, 0);
    }
  }
  __syncthreads();
  for (int rt = 0; rt < 2; rt++)
    for (int tt = 0; tt < 4; tt++)
      for (int r = 0; r < 4; r++)
        rowX[(mrow + rt * 16 + quad * 4 + r) * LDP + chalf + tt * 16 + lc] = f2bf(acc[rt][tt][r]);
  __syncthreads();
  {
    int r = tid >> 2, kg = (tid & 3) * 32;
    int gr = r0 + r;
    if (gr < N) {
      uint4* gp = (uint4*)(featb + (size_t)gr * NCH + kg);
      const uint4* l = (const uint4*)&rowX[r * LDP + kg];
      for (int i = 0; i < 4; i++) gp[i] = l[i];
    }
  }
  // fused er: 512 (row,head) pairs from the LDS featb tile
  for (int p = tid; p < 512; p += 256) {
    int row = p >> 3, h = p & 7;
    int gr = r0 + row;
    if (gr < N) {
      const unsigned* rp = (const unsigned*)&rowX[row * LDP + h * 16];
      float sr = 0.f;
      for (int q = 0; q < 8; q++) {
        unsigned u = rp[q];
        int c = h * 16 + 2 * q;
        sr += bflo(u) * arL[c] + bfhi(u) * arL[c + 1];
      }
      er[gr * NH + h] = sr;
    }
  }
}

// ---------------- counting sort of edges by dst ----------------
__global__ void scan_part(const int* __restrict__ cnt, int* __restrict__ off,
                          int* __restrict__ bsum, int N) {
  __shared__ int sh[256];
  int t = threadIdx.x, i = blockIdx.x * 256 + t;
  int v = (i < N) ? cnt[i] : 0;
  sh[t] = v; __syncthreads();
  for (int d = 1; d < 256; d <<= 1) {
    int u = (t >= d) ? sh[t - d] : 0;
    __syncthreads();
    sh[t] += u;
    __syncthreads();
  }
  if (i < N) off[i] = sh[t] - v;
  if (t == 255) bsum[blockIdx.x] = sh[255];
}

// scan_add with built-in top-level scan; also initializes per-bucket cursor
__global__ void scan_add2(int* __restrict__ off, const int* __restrict__ bsum,
                          int* __restrict__ bktcur, int N, int nb) {
  __shared__ int sh[256];
  int t = threadIdx.x;
  int v = (t < nb) ? bsum[t] : 0;
  sh[t] = v; __syncthreads();
  for (int d = 1; d < 256; d <<= 1) {
    int u = (t >= d) ? sh[t - d] : 0;
    __syncthreads();
    sh[t] += u;
    __syncthreads();
  }
  int pref = (blockIdx.x > 0) ? sh[blockIdx.x - 1] : 0;
  int i = blockIdx.x * 256 + t;
  if (i < N) {
    int w = off[i] + pref;
    off[i] = w;
    if (t == 0) bktcur[blockIdx.x] = w;
  }
}

// ---------------- pass 1: bin edges by dst>>8 into bucket-major (src,dst) runs ----------------
__global__ __launch_bounds__(256) void bin_scatter(const int* __restrict__ src,
                                                   const int* __restrict__ dst,
                                                   int* __restrict__ bktcur,
                                                   uint2* __restrict__ ebuf, int E) {
  __shared__ int bc[256];
  __shared__ int bbase[256];
  int tid = threadIdx.x;
  int s = blockIdx.x * CHUNK;
  int e = min(s + CHUNK, E);
  bc[tid] = 0;
  __syncthreads();
  for (int i = s + tid; i < e; i += 256) atomicAdd(&bc[dst[i] >> 8], 1);
  __syncthreads();
  int c = bc[tid];
  if (c > 0) bbase[tid] = atomicAdd(&bktcur[tid], c);
  __syncthreads();
  bc[tid] = 0;
  __syncthreads();
  for (int i = s + tid; i < e; i += 256) {
    int d = dst[i];
    int b = d >> 8;
    int r = atomicAdd(&bc[b], 1);
    ebuf[bbase[b] + r] = make_uint2((unsigned)src[i], (unsigned)d);
  }
}

// ---------------- pass 2: per-bucket final scatter with LDS cursors ----------------
__global__ __launch_bounds__(256) void final_scatter(const uint2* __restrict__ ebuf,
                                                     const int* __restrict__ off,
                                                     int* __restrict__ ssrc,
                                                     int E, int N, int NBK) {
  __shared__ int lcur[256];
  __shared__ int sbeg, send;
  int tid = threadIdx.x;
  int b = blockIdx.x;
  int n0 = b * 256;
  int node = n0 + tid;
  lcur[tid] = (node < N) ? off[node] : 0;
  if (tid == 0) {
    sbeg = off[n0];
    send = (b == NBK - 1) ? E : off[n0 + 256];
  }
  __syncthreads();
  int beg = sbeg, end = send;
  for (int i = beg + tid; i < end; i += 256) {
    uint2 ed = ebuf[i];
    int r = atomicAdd(&lcur[(int)ed.y - n0], 1);
    ssrc[r] = (int)ed.x;
  }
}

// ---------------- gather + skip + bias + fused BN1 stats ----------------
__global__ __launch_bounds__(256) void gat_gather7(const int* __restrict__ ssrc,
                                                   const int* __restrict__ off,
                                                   const int* __restrict__ cnt,
                                                   const float* __restrict__ attn_l,
                                                   const float* __restrict__ er,
                                                   const unsigned short* __restrict__ featb,
                                                   const float* __restrict__ x,
                                                   const float* __restrict__ gatb,
                                                   float* __restrict__ hbuf,
                                                   float* __restrict__ stats, int N) {
  __shared__ float ps[4][128], pq[4][128];
  int tid = threadIdx.x;
  int lane = tid & 63, w = tid >> 6;
  int hme = lane >> 3;         // head of this lane's channel pair
  int c0 = 2 * lane;
  float2 al2 = *(const float2*)(attn_l + c0);
  float alx = al2.x, aly = al2.y;
  float gb0 = gatb[c0], gb1 = gatb[c0 + 1];
  float s0 = 0.f, s1 = 0.f, q0 = 0.f, q1 = 0.f;
  int base = blockIdx.x * (4 * NPW) + w * NPW;
  for (int j = 0; j < NPW; j++) {
    int node = base + j;
    if (node >= N) break;
    node = __builtin_amdgcn_readfirstlane(node);
    float erh = er[node * NH + hme];
    int beg = __builtin_amdgcn_readfirstlane(off[node]);
    int num = __builtin_amdgcn_readfirstlane(cnt[node]);
    const int* sp = ssrc + beg;
    float acc0 = 0.f, acc1 = 0.f, den = 0.f;
    int i = 0;
    for (; i + 8 <= num; i += 8) {
      int n0 = __builtin_amdgcn_readfirstlane(sp[i + 0]);
      int n1 = __builtin_amdgcn_readfirstlane(sp[i + 1]);
      int n2 = __builtin_amdgcn_readfirstlane(sp[i + 2]);
      int n3 = __builtin_amdgcn_readfirstlane(sp[i + 3]);
      int n4 = __builtin_amdgcn_readfirstlane(sp[i + 4]);
      int n5 = __builtin_amdgcn_readfirstlane(sp[i + 5]);
      int n6 = __builtin_amdgcn_readfirstlane(sp[i + 6]);
      int n7 = __builtin_amdgcn_readfirstlane(sp[i + 7]);
      unsigned f0 = ((const unsigned*)(featb + (size_t)n0 * NCH))[lane];
      unsigned f1 = ((const unsigned*)(featb + (size_t)n1 * NCH))[lane];
      unsigned f2 = ((const unsigned*)(featb + (size_t)n2 * NCH))[lane];
      unsigned f3 = ((const unsigned*)(featb + (size_t)n3 * NCH))[lane];
      unsigned f4 = ((const unsigned*)(featb + (size_t)n4 * NCH))[lane];
      unsigned f5 = ((const unsigned*)(featb + (size_t)n5 * NCH))[lane];
      unsigned f6 = ((const unsigned*)(featb + (size_t)n6 * NCH))[lane];
      unsigned f7 = ((const unsigned*)(featb + (size_t)n7 * NCH))[lane];
      // in-register el: per-lane partial then butterfly over the 8-lane head group
      float p0 = bflo(f0) * alx + bfhi(f0) * aly;
      float p1 = bflo(f1) * alx + bfhi(f1) * aly;
      float p2 = bflo(f2) * alx + bfhi(f2) * aly;
      float p3 = bflo(f3) * alx + bfhi(f3) * aly;
      float p4 = bflo(f4) * alx + bfhi(f4) * aly;
      float p5 = bflo(f5) * alx + bfhi(f5) * aly;
      float p6 = bflo(f6) * alx + bfhi(f6) * aly;
      float p7 = bflo(f7) * alx + bfhi(f7) * aly;
      p0 += __shfl_xor(p0, 1); p1 += __shfl_xor(p1, 1);
      p2 += __shfl_xor(p2, 1); p3 += __shfl_xor(p3, 1);
      p4 += __shfl_xor(p4, 1); p5 += __shfl_xor(p5, 1);
      p6 += __shfl_xor(p6, 1); p7 += __shfl_xor(p7, 1);
      p0 += __shfl_xor(p0, 2); p1 += __shfl_xor(p1, 2);
      p2 += __shfl_xor(p2, 2); p3 += __shfl_xor(p3, 2);
      p4 += __shfl_xor(p4, 2); p5 += __shfl_xor(p5, 2);
      p6 += __shfl_xor(p6, 2); p7 += __shfl_xor(p7, 2);
      p0 += __shfl_xor(p0, 4); p1 += __shfl_xor(p1, 4);
      p2 += __shfl_xor(p2, 4); p3 += __shfl_xor(p3, 4);
      p4 += __shfl_xor(p4, 4); p5 += __shfl_xor(p5, 4);
      p6 += __shfl_xor(p6, 4); p7 += __shfl_xor(p7, 4);
      float e0 = p0 + erh, e1 = p1 + erh, e2 = p2 + erh, e3 = p3 + erh;
      float e4 = p4 + erh, e5 = p5 + erh, e6 = p6 + erh, e7 = p7 + erh;
      e0 = e0 > 0.f ? e0 : SLOPE * e0;  e1 = e1 > 0.f ? e1 : SLOPE * e1;
      e2 = e2 > 0.f ? e2 : SLOPE * e2;  e3 = e3 > 0.f ? e3 : SLOPE * e3;
      e4 = e4 > 0.f ? e4 : SLOPE * e4;  e5 = e5 > 0.f ? e5 : SLOPE * e5;
      e6 = e6 > 0.f ? e6 : SLOPE * e6;  e7 = e7 > 0.f ? e7 : SLOPE * e7;
      float w0 = __expf(e0), w1 = __expf(e1), w2 = __expf(e2), w3 = __expf(e3);
      float w4 = __expf(e4), w5 = __expf(e5), w6 = __expf(e6), w7 = __expf(e7);
      acc0 += w0 * bflo(f0) + w1 * bflo(f1) + w2 * bflo(f2) + w3 * bflo(f3)
            + w4 * bflo(f4) + w5 * bflo(f5) + w6 * bflo(f6) + w7 * bflo(f7);
      acc1 += w0 * bfhi(f0) + w1 * bfhi(f1) + w2 * bfhi(f2) + w3 * bfhi(f3)
            + w4 * bfhi(f4) + w5 * bfhi(f5) + w6 * bfhi(f6) + w7 * bfhi(f7);
      den  += w0 + w1 + w2 + w3 + w4 + w5 + w6 + w7;
    }
    for (; i < num; i++) {
      int s = __builtin_amdgcn_readfirstlane(sp[i]);
      unsigned f = ((const unsigned*)(featb + (size_t)s * NCH))[lane];
      float p = bflo(f) * alx + bfhi(f) * aly;
      p += __shfl_xor(p, 1); p += __shfl_xor(p, 2); p += __shfl_xor(p, 4);
      float e = p + erh;
      e = e > 0.f ? e : SLOPE * e;
      float wv = __expf(e);
      acc0 += wv * bflo(f); acc1 += wv * bfhi(f); den += wv;
    }
    float inv = den > 0.f ? 1.f / den : 0.f;
    float2 xv = *(const float2*)(x + (size_t)node * NCH + c0);
    float h0 = xv.x + acc0 * inv + gb0;
    float h1 = xv.y + acc1 * inv + gb1;
    *(float2*)(hbuf + (size_t)node * NCH + c0) = make_float2(h0, h1);
    s0 += h0; s1 += h1; q0 += h0 * h0; q1 += h1 * h1;
  }
  ps[w][c0] = s0; ps[w][c0 + 1] = s1;
  pq[w][c0] = q0; pq[w][c0 + 1] = q1;
  __syncthreads();
  if (tid < 128) {
    float ss = ps[0][tid] + ps[1][tid] + ps[2][tid] + ps[3][tid];
    float qq = pq[0][tid] + pq[1][tid] + pq[2][tid] + pq[3][tid];
    int rep = blockIdx.x & 7;   // 8-way replicated, CONTIGUOUS (few dirty lines)
    atomicAdd(&stats[rep * 128 + tid], ss);
    atomicAdd(&stats[1024 + rep * 128 + tid], qq);
  }
}

// ---------------- fused BN1-finalize + BN1 + FFN: hid^T trick, rowA in registers ----------------
__global__ __launch_bounds__(512, 4) void ffn_mfma2(const float* __restrict__ hbuf,
                                                    const float* __restrict__ g1, const float* __restrict__ be1,
                                                    const unsigned short* __restrict__ w1f,
                                                    const unsigned short* __restrict__ w2f,
                                                    const float* __restrict__ b1, const float* __restrict__ b2,
                                                    float* __restrict__ t, float* __restrict__ stats, int N) {
  __shared__ unsigned short w1t[16384];   // 32 KB (chunk weights; reused as BN1-row stash in epilogue)
  __shared__ unsigned short w2t[16384];   // 32 KB
  __shared__ unsigned short scr[8][512];  // 8 KB wave-private transpose scratch (1 frag)
  __shared__ float b1L[512];              // 2 KB
  __shared__ float psc[128], psh[128], b2L[128], csum[128], csq[128];  // 2.5 KB
  int tid = threadIdx.x;
  int lane = tid & 63, wid = tid >> 6;
  int quad = lane >> 4, lc = lane & 15;
  int r0 = blockIdx.x * 128;

  b1L[tid] = b1[tid];
  if (tid < 128) {
    float s = 0.f, sq = 0.f;
    for (int r = 0; r < 8; r++) {
      s  += stats[r * 128 + tid];
      sq += stats[1024 + r * 128 + tid];
    }
    float m = s / (float)N;
    float v = sq / (float)N - m * m;
    float rsv = rsqrtf(v + BN_EPS);
    float scv = g1[tid] * rsv;
    psc[tid] = scv;
    psh[tid] = be1[tid] - scv * m;
    b2L[tid] = b2[tid];
    csum[tid] = 0.f; csq[tid] = 0.f;
  }

  int arow = r0 + wid * 16 + lc;
  float4 av[4][2];
  for (int kk = 0; kk < 4; kk++) {
    if (arow < N) {
      const float4* p = (const float4*)(hbuf + (size_t)arow * NCH + kk * 32 + quad * 8);
      av[kk][0] = p[0]; av[kk][1] = p[1];
    } else {
      av[kk][0] = make_float4(0.f, 0.f, 0.f, 0.f);
      av[kk][1] = make_float4(0.f, 0.f, 0.f, 0.f);
    }
  }
  __syncthreads();   // psc/psh ready

  short8 rowA[4];
  for (int kk = 0; kk < 4; kk++) {
    int c = kk * 32 + quad * 8;
    float4 s0 = *(float4*)&psc[c], s1 = *(float4*)&psc[c + 4];
    float4 h0 = *(float4*)&psh[c], h1 = *(float4*)&psh[c + 4];
    short8 r;
    r[0] = (short)f2bf(av[kk][0].x * s0.x + h0.x);
    r[1] = (short)f2bf(av[kk][0].y * s0.y + h0.y);
    r[2] = (short)f2bf(av[kk][0].z * s0.z + h0.z);
    r[3] = (short)f2bf(av[kk][0].w * s0.w + h0.w);
    r[4] = (short)f2bf(av[kk][1].x * s1.x + h1.x);
    r[5] = (short)f2bf(av[kk][1].y * s1.y + h1.y);
    r[6] = (short)f2bf(av[kk][1].z * s1.z + h1.z);
    r[7] = (short)f2bf(av[kk][1].w * s1.w + h1.w);
    rowA[kk] = r;
  }

  floatx4 acc2[8];
  for (int nt = 0; nt < 8; nt++) acc2[nt] = (floatx4)(0.f);

  for (int ch = 0; ch < 4; ch++) {
    __syncthreads();
    {
      const uint4* g1p = (const uint4*)(w1f + ch * 16384);
      const uint4* g2p = (const uint4*)(w2f + ch * 16384);
      uint4* l1 = (uint4*)w1t;
      uint4* l2 = (uint4*)w2t;
      for (int r = 0; r < 4; r++) {
        l1[tid + r * 512] = g1p[tid + r * 512];
        l2[tid + r * 512] = g2p[tid + r * 512];
      }
    }
    __syncthreads();

    for (int kk = 0; kk < 4; kk++) {
      floatx4 d0 = (floatx4)(0.f), d1 = (floatx4)(0.f);
      int t0 = 2 * kk, t1 = 2 * kk + 1;
      for (int kp = 0; kp < 4; kp++) {
        short8 a0 = *(const short8*)&w1t[(t0 * 4 + kp) * 512 + lane * 8];
        short8 a1 = *(const short8*)&w1t[(t1 * 4 + kp) * 512 + lane * 8];
        d0 = __builtin_amdgcn_mfma_f32_16x16x32_bf16(a0, rowA[kp], d0, 0, 0, 0);
        d1 = __builtin_amdgcn_mfma_f32_16x16x32_bf16(a1, rowA[kp], d1, 0, 0, 0);
      }
      {
        int bi0 = ch * 128 + t0 * 16 + 4 * quad;
        float4 bv0 = *(float4*)&b1L[bi0];
        float4 bv1 = *(float4*)&b1L[bi0 + 16];
        float v0, v1, v2, v3;
        unsigned lo, hi;
        int sidx;
        v0 = fmaxf(d0[0] + bv0.x, 0.f); v1 = fmaxf(d0[1] + bv0.y, 0.f);
        v2 = fmaxf(d0[2] + bv0.z, 0.f); v3 = fmaxf(d0[3] + bv0.w, 0.f);
        lo = (unsigned)f2bf(v0) | ((unsigned)f2bf(v1) << 16);
        hi = (unsigned)f2bf(v2) | ((unsigned)f2bf(v3) << 16);
        sidx = ((quad >> 1) * 16 + lc) * 8 + 4 * (quad & 1);
        *(uint2*)&scr[wid][sidx] = make_uint2(lo, hi);
        v0 = fmaxf(d1[0] + bv1.x, 0.f); v1 = fmaxf(d1[1] + bv1.y, 0.f);
        v2 = fmaxf(d1[2] + bv1.z, 0.f); v3 = fmaxf(d1[3] + bv1.w, 0.f);
        lo = (unsigned)f2bf(v0) | ((unsigned)f2bf(v1) << 16);
        hi = (unsigned)f2bf(v2) | ((unsigned)f2bf(v3) << 16);
        sidx = ((2 + (quad >> 1)) * 16 + lc) * 8 + 4 * (quad & 1);
        *(uint2*)&scr[wid][sidx] = make_uint2(lo, hi);
      }
      short8 a2 = *(const short8*)&scr[wid][lane * 8];
      for (int nt = 0; nt < 8; nt++) {
        short8 bfr = *(const short8*)&w2t[(nt * 4 + kk) * 512 + lane * 8];
        acc2[nt] = __builtin_amdgcn_mfma_f32_16x16x32_bf16(a2, bfr, acc2[nt], 0, 0, 0);
      }
    }
  }

  __syncthreads();   // all waves done reading w1t/w2t
  {
    unsigned short* stash = w1t;  // [wave][row16][col]
    for (int kk = 0; kk < 4; kk++)
      *(short8*)&stash[wid * 2048 + lc * 128 + kk * 32 + quad * 8] = rowA[kk];
  }
  __syncthreads();

  for (int nt = 0; nt < 8; nt++) {
    int col = nt * 16 + lc;
    float b2v = b2L[col];
    float s = 0.f, q = 0.f;
    for (int reg = 0; reg < 4; reg++) {
      int grow = r0 + wid * 16 + quad * 4 + reg;
      if (grow < N) {
        float base = bflo((unsigned)w1t[wid * 2048 + (quad * 4 + reg) * 128 + col]);
        float tv = base + acc2[nt][reg] + b2v;
        t[(size_t)grow * NCH + col] = tv;
        s += tv; q += tv * tv;
      }
    }
    s += __shfl_xor(s, 16); s += __shfl_xor(s, 32);
    q += __shfl_xor(q, 16); q += __shfl_xor(q, 32);
    if (quad == 0) { atomicAdd(&csum[col], s); atomicAdd(&csq[col], q); }
  }
  __syncthreads();
  if (tid < 128) {
    atomicAdd(&stats[16384 + tid * 16], csum[tid]);
    atomicAdd(&stats[18432 + tid * 16], csq[tid]);
  }
}

// ---------------- BN2 finalize + apply -> out (float4 vectorized) ----------------
__global__ __launch_bounds__(256) void bn2_apply2(const float* __restrict__ t,
                                                  const float* __restrict__ g, const float* __restrict__ b,
                                                  const float* __restrict__ stats,
                                                  float* __restrict__ out, int N) {
  __shared__ float scs[128], shs[128];
  int tid = threadIdx.x;
  if (tid < 128) {
    float s = stats[16384 + tid * 16], sq = stats[18432 + tid * 16];
    float m = s / (float)N;
    float v = sq / (float)N - m * m;
    float rsv = rsqrtf(v + BN_EPS);
    float gg = g[tid] * rsv;
    scs[tid] = gg;
    shs[tid] = b[tid] - gg * m;
  }
  __syncthreads();
  int i = blockIdx.x * 256 + tid;
  int tot4 = N * 32;   // N*128/4
  if (i < tot4) {
    float4 v = ((const float4*)t)[i];
    int c = (i & 31) * 4;
    float4 o;
    o.x = v.x * scs[c + 0] + shs[c + 0];
    o.y = v.y * scs[c + 1] + shs[c + 1];
    o.z = v.z * scs[c + 2] + shs[c + 2];
    o.w = v.w * scs[c + 3] + shs[c + 3];
    ((float4*)out)[i] = o;
  }
}

extern "C" void kernel_launch(void* const* d_in, const int* in_sizes, int n_in,
                              void* d_out, int out_size, void* d_ws, size_t ws_size,
                              hipStream_t stream) {
  const float* x       = (const float*)d_in[0];
  const int*   src     = (const int*)d_in[1];
  const int*   dst     = (const int*)d_in[2];
  const float* W       = (const float*)d_in[3];
  const float* attn_l  = (const float*)d_in[4];
  const float* attn_r  = (const float*)d_in[5];
  const float* gatb    = (const float*)d_in[6];
  const float* gamma1  = (const float*)d_in[7];
  const float* beta1   = (const float*)d_in[8];
  const float* gamma2  = (const float*)d_in[9];
  const float* beta2   = (const float*)d_in[10];
  const float* W1      = (const float*)d_in[11];
  const float* b1      = (const float*)d_in[12];
  const float* W2      = (const float*)d_in[13];
  const float* b2      = (const float*)d_in[14];
  float* out = (float*)d_out;

  const int N = in_sizes[0] / NCH;   // 50000
  const int E = in_sizes[1];         // 800000
  const int nb = (N + 255) / 256;    // scan blocks == bucket count
  const int EB = (E + 255) / 256;    // edge blocks (hist)
  const int FB = (N + 63) / 64;      // feat blocks
  const int BB = (E + CHUNK - 1) / CHUNK;  // bin_scatter blocks

  float* hbuf  = (float*)d_ws;             // N*128 f32 (pre-BN1 h)
  float* t     = hbuf + (size_t)N * NCH;   // N*128 f32 (pre-BN2 t)
  float* er    = t + (size_t)N * NCH;      // N*8
  float* stats = er + (size_t)N * NH;      // 20480 floats (BN1 8-rep contiguous + BN2)
  unsigned short* featb = (unsigned short*)(stats + 20480);  // N*128 bf16
  unsigned short* WT    = featb + (size_t)N * NCH;           // 128*128 bf16
  unsigned short* w1f   = WT + NCH * NCH;                    // 512*128 bf16 (frag order)
  unsigned short* w2f   = w1f + HID * NCH;                   // 128*512 bf16 (frag order)
  int* cnt    = (int*)(w2f + HID * NCH);                     // N
  int* off    = cnt + N;                                     // N
  int* bktcur = off + N;                                     // 256
  int* bsum   = bktcur + 256;                                // 256
  int* ssrc   = bsum + 256;                                  // E
  uint2* ebuf = (uint2*)(ssrc + E);                          // E uint2 (8B each)

  const int cb = (((N + 3) / 4) + 255) / 256;
  prep_all<<<596 + cb, 256, 0, stream>>>(W, WT, W1, w1f, W2, w2f, stats, cnt, N);

  feat_hist<<<FB + EB, 256, 0, stream>>>(x, WT, attn_r, featb, er, N, dst, cnt, E, FB);

  scan_part<<<nb, 256, 0, stream>>>(cnt, off, bsum, N);
  scan_add2<<<nb, 256, 0, stream>>>(off, bsum, bktcur, N, nb);

  bin_scatter<<<BB, 256, 0, stream>>>(src, dst, bktcur, ebuf, E);
  final_scatter<<<nb, 256, 0, stream>>>(ebuf, off, ssrc, E, N, nb);

  gat_gather7<<<(N + 4 * NPW - 1) / (4 * NPW), 256, 0, stream>>>(ssrc, off, cnt, attn_l, er,
                                                                 featb, x, gatb, hbuf, stats, N);

  ffn_mfma2<<<(N + 127) / 128, 512, 0, stream>>>(hbuf, gamma1, beta1,
                                                 w1f, w2f, b1, b2, t, stats, N);

  bn2_apply2<<<(N * 32 + 255) / 256, 256, 0, stream>>>(t, gamma2, beta2, stats, out, N);
}